// Round 1
// baseline (329.002 us; speedup 1.0000x reference)
//
#include <hip/hip_runtime.h>
#include <math.h>

#define NROWS 8192
#define FIN   512
#define FOUT  256
#define NCHUNK 256
#define CHROWS 32   // NROWS / NCHUNK

// ---------------- GEMM: h = x @ W (fp32, 64x64 tile, 4x4 per thread) ----------------
__global__ __launch_bounds__(256) void gemm_h(const float* __restrict__ x,
                                              const float* __restrict__ W,
                                              float* __restrict__ h) {
    __shared__ float As[16][64];
    __shared__ float Bs[16][64];
    const int tid = threadIdx.x;
    const int tx = tid & 15, ty = tid >> 4;
    const int m0 = blockIdx.y * 64;
    const int n0 = blockIdx.x * 64;
    const int lm = tid >> 2;          // 0..63 row within x tile
    const int lk = (tid & 3) * 4;     // k offset within 16
    const int wk = tid >> 4;          // 0..15 k row for W tile
    const int wn = (tid & 15) * 4;    // col offset within 64
    float acc[4][4] = {};
    for (int k0 = 0; k0 < FIN; k0 += 16) {
        float4 xa = *(const float4*)&x[(size_t)(m0 + lm) * FIN + k0 + lk];
        float4 wb = *(const float4*)&W[(size_t)(k0 + wk) * FOUT + n0 + wn];
        __syncthreads();
        As[lk + 0][lm] = xa.x;
        As[lk + 1][lm] = xa.y;
        As[lk + 2][lm] = xa.z;
        As[lk + 3][lm] = xa.w;
        *(float4*)&Bs[wk][wn] = wb;
        __syncthreads();
#pragma unroll
        for (int kk = 0; kk < 16; ++kk) {
            float av[4], bv[4];
            *(float4*)av = *(const float4*)&As[kk][ty * 4];
            *(float4*)bv = *(const float4*)&Bs[kk][tx * 4];
#pragma unroll
            for (int i = 0; i < 4; ++i)
#pragma unroll
                for (int j = 0; j < 4; ++j)
                    acc[i][j] = fmaf(av[i], bv[j], acc[i][j]);
        }
    }
#pragma unroll
    for (int i = 0; i < 4; ++i) {
        float4 v = make_float4(acc[i][0], acc[i][1], acc[i][2], acc[i][3]);
        *(float4*)&h[(size_t)(m0 + ty * 4 + i) * FOUT + n0 + tx * 4] = v;
    }
}

// ---------------- f = h@a1, g = h@a2 (block per row) ----------------
__global__ __launch_bounds__(256) void fg_kernel(const float* __restrict__ h,
                                                 const float* __restrict__ a,
                                                 float* __restrict__ f,
                                                 float* __restrict__ g) {
    const int i = blockIdx.x;
    const int c = threadIdx.x;
    float v = h[(size_t)i * FOUT + c];
    float p = v * a[c];
    float q = v * a[FOUT + c];
#pragma unroll
    for (int off = 32; off >= 1; off >>= 1) {
        p += __shfl_down(p, off, 64);
        q += __shfl_down(q, off, 64);
    }
    __shared__ float sp[4], sq[4];
    const int lane = c & 63, wid = c >> 6;
    if (lane == 0) { sp[wid] = p; sq[wid] = q; }
    __syncthreads();
    if (c == 0) {
        f[i] = sp[0] + sp[1] + sp[2] + sp[3];
        g[i] = sq[0] + sq[1] + sq[2] + sq[3];
    }
}

// ---------------- g_max ----------------
__global__ __launch_bounds__(256) void gmax_kernel(const float* __restrict__ g,
                                                   float* __restrict__ gmax) {
    const int t = threadIdx.x;
    float m = -1e30f;
    for (int r = t; r < NROWS; r += 256) m = fmaxf(m, g[r]);
#pragma unroll
    for (int off = 32; off >= 1; off >>= 1) m = fmaxf(m, __shfl_down(m, off, 64));
    __shared__ float sm[4];
    if ((t & 63) == 0) sm[t >> 6] = m;
    __syncthreads();
    if (t == 0) *gmax = fmaxf(fmaxf(sm[0], sm[1]), fmaxf(sm[2], sm[3]));
}

// ---------------- single-block bitonic sort of (g, idx) ----------------
__global__ __launch_bounds__(1024) void sort_kernel(const float* __restrict__ g,
                                                    float* __restrict__ gs,
                                                    int* __restrict__ perm) {
    __shared__ float key[NROWS];
    __shared__ unsigned short id[NROWS];
    const int tid = threadIdx.x;
    for (int r = tid; r < NROWS; r += 1024) { key[r] = g[r]; id[r] = (unsigned short)r; }
    for (int k = 2; k <= NROWS; k <<= 1) {
        for (int j = k >> 1; j > 0; j >>= 1) {
            __syncthreads();
            for (int i = tid; i < NROWS; i += 1024) {
                const int l = i ^ j;
                if (l > i) {
                    const bool up = ((i & k) == 0);
                    float ki = key[i], kl = key[l];
                    if (up ? (ki > kl) : (ki < kl)) {
                        key[i] = kl; key[l] = ki;
                        unsigned short t = id[i]; id[i] = id[l]; id[l] = t;
                    }
                }
            }
        }
    }
    __syncthreads();
    for (int r = tid; r < NROWS; r += 1024) { gs[r] = key[r]; perm[r] = (int)id[r]; }
}

// ---------------- permute h into sorted order; compute weights ----------------
__global__ __launch_bounds__(256) void permute_kernel(const float* __restrict__ h,
                                                      const int* __restrict__ perm,
                                                      const float* __restrict__ gs,
                                                      const float* __restrict__ gmax,
                                                      float* __restrict__ hs,
                                                      float* __restrict__ wv) {
    const int r = blockIdx.x, c = threadIdx.x;
    const int src = perm[r];
    hs[(size_t)r * FOUT + c] = h[(size_t)src * FOUT + c];
    if (c == 0) wv[r] = expf(gs[r] - *gmax);
}

// ---------------- scans (3 passes) ----------------
__global__ __launch_bounds__(256) void scan_pass1(const float* __restrict__ hs,
                                                  const float* __restrict__ wv,
                                                  float* __restrict__ c0,
                                                  float* __restrict__ c1,
                                                  float* __restrict__ c1s) {
    const int k = blockIdx.x, c = threadIdx.x;
    const int base = k * CHROWS;
    float s0 = 0.f, s1 = 0.f;
    for (int r = 0; r < CHROWS; ++r) {
        float v = hs[(size_t)(base + r) * FOUT + c];
        float w = wv[base + r];
        s0 += v;
        s1 += w * v;
    }
    c0[k * FOUT + c] = s0;
    c1[k * FOUT + c] = s1;
    if (c == 0) {
        float t = 0.f;
        for (int r = 0; r < CHROWS; ++r) t += wv[base + r];
        c1s[k] = t;
    }
}

__global__ __launch_bounds__(256) void scan_pass2(const float* __restrict__ c0,
                                                  const float* __restrict__ c1,
                                                  const float* __restrict__ c1s,
                                                  float* __restrict__ o0,
                                                  float* __restrict__ o1,
                                                  float* __restrict__ o1s) {
    const int c = threadIdx.x;
    float run = 0.f;
    for (int k = 0; k < NCHUNK; ++k) { o0[k * FOUT + c] = run; run += c0[k * FOUT + c]; }
    float run1 = 0.f;
    for (int k = NCHUNK - 1; k >= 0; --k) { o1[k * FOUT + c] = run1; run1 += c1[k * FOUT + c]; }
    if (c == 0) {
        float rs = 0.f;
        for (int k = NCHUNK - 1; k >= 0; --k) { o1s[k] = rs; rs += c1s[k]; }
    }
}

__global__ __launch_bounds__(256) void scan_pass3(const float* __restrict__ hs,
                                                  const float* __restrict__ wv,
                                                  const float* __restrict__ o0,
                                                  const float* __restrict__ o1,
                                                  const float* __restrict__ o1s,
                                                  float* __restrict__ P0,
                                                  float* __restrict__ S1,
                                                  float* __restrict__ S1s) {
    const int k = blockIdx.x, c = threadIdx.x;
    const int base = k * CHROWS;
    float run0 = o0[k * FOUT + c];
    for (int r = 0; r < CHROWS; ++r) {
        P0[(size_t)(base + r) * FOUT + c] = run0;
        run0 += hs[(size_t)(base + r) * FOUT + c];
    }
    float run1 = o1[k * FOUT + c];
    for (int r = CHROWS - 1; r >= 0; --r) {
        float w = wv[base + r];
        float v = hs[(size_t)(base + r) * FOUT + c];
        run1 += w * v;
        S1[(size_t)(base + r) * FOUT + c] = run1;
    }
    if (c == 0) {
        float rs = o1s[k];
        for (int r = CHROWS - 1; r >= 0; --r) { rs += wv[base + r]; S1s[base + r] = rs; }
    }
    if (k == NCHUNK - 1) {
        P0[(size_t)NROWS * FOUT + c] = run0;   // total sum
        S1[(size_t)NROWS * FOUT + c] = 0.f;
        if (c == 0) S1s[NROWS] = 0.f;
    }
}

// ---------------- final: per-row combine + ELU ----------------
__global__ __launch_bounds__(256) void final_kernel(const float* __restrict__ f,
                                                    const float* __restrict__ gs,
                                                    const float* __restrict__ gmaxp,
                                                    const float* __restrict__ P0,
                                                    const float* __restrict__ S1,
                                                    const float* __restrict__ S1s,
                                                    float* __restrict__ out) {
    const int i = blockIdx.x, c = threadIdx.x;
    const float fi = f[i];
    const float gm = *gmaxp;
    const float t = -fi;
    int lo = 0, hi = NROWS;
    while (lo < hi) {
        int mid = (lo + hi) >> 1;
        if (gs[mid] <= t) lo = mid + 1; else hi = mid;
    }
    const int n0 = lo;  // count of g_j <= -f_i
    const float m = fmaxf(0.f, fi + gm);
    const float A = expf(-m);            // weight of relu-clipped group
    const float B = expf(fi + gm - m);   // scale of exp group
    const float denom = A * (float)n0 + B * S1s[n0];
    const float numer = A * P0[(size_t)n0 * FOUT + c] + B * S1[(size_t)n0 * FOUT + c];
    const float v = numer / denom;
    out[(size_t)i * FOUT + c] = v > 0.f ? v : expm1f(v);
}

extern "C" void kernel_launch(void* const* d_in, const int* in_sizes, int n_in,
                              void* d_out, int out_size, void* d_ws, size_t ws_size,
                              hipStream_t stream) {
    (void)in_sizes; (void)n_in; (void)out_size; (void)ws_size;
    const float* x = (const float*)d_in[0];
    const float* W = (const float*)d_in[1];
    const float* a = (const float*)d_in[2];
    float* out = (float*)d_out;

    char* ws = (char*)d_ws;
    size_t off = 0;
    auto alloc = [&](size_t bytes) -> void* {
        void* p = ws + off;
        off += (bytes + 255) & ~(size_t)255;
        return p;
    };
    float* h    = (float*)alloc((size_t)NROWS * FOUT * 4);
    float* hs   = (float*)alloc((size_t)NROWS * FOUT * 4);
    float* P0   = (float*)alloc((size_t)(NROWS + 1) * FOUT * 4);
    float* S1   = (float*)alloc((size_t)(NROWS + 1) * FOUT * 4);
    float* f    = (float*)alloc(NROWS * 4);
    float* g    = (float*)alloc(NROWS * 4);
    float* gs   = (float*)alloc(NROWS * 4);
    int*   perm = (int*)alloc(NROWS * 4);
    float* wv   = (float*)alloc(NROWS * 4);
    float* c0   = (float*)alloc(NCHUNK * FOUT * 4);
    float* c1   = (float*)alloc(NCHUNK * FOUT * 4);
    float* o0   = (float*)alloc(NCHUNK * FOUT * 4);
    float* o1   = (float*)alloc(NCHUNK * FOUT * 4);
    float* c1s  = (float*)alloc(NCHUNK * 4);
    float* o1s  = (float*)alloc(NCHUNK * 4);
    float* S1s  = (float*)alloc((NROWS + 1) * 4);
    float* gmaxp= (float*)alloc(4);

    gemm_h<<<dim3(FOUT / 64, NROWS / 64), 256, 0, stream>>>(x, W, h);
    fg_kernel<<<NROWS, 256, 0, stream>>>(h, a, f, g);
    gmax_kernel<<<1, 256, 0, stream>>>(g, gmaxp);
    sort_kernel<<<1, 1024, 0, stream>>>(g, gs, perm);
    permute_kernel<<<NROWS, 256, 0, stream>>>(h, perm, gs, gmaxp, hs, wv);
    scan_pass1<<<NCHUNK, 256, 0, stream>>>(hs, wv, c0, c1, c1s);
    scan_pass2<<<1, 256, 0, stream>>>(c0, c1, c1s, o0, o1, o1s);
    scan_pass3<<<NCHUNK, 256, 0, stream>>>(hs, wv, o0, o1, o1s, P0, S1, S1s);
    final_kernel<<<NROWS, 256, 0, stream>>>(f, gs, gmaxp, P0, S1, S1s, out);
}

// Round 2
// 190.531 us; speedup vs baseline: 1.7268x; 1.7268x over previous
//
#include <hip/hip_runtime.h>
#include <math.h>

#define NROWS 8192
#define FIN   512
#define FOUT  256
#define NCHUNK 256
#define CHROWS 32   // NROWS / NCHUNK

// ---------------- GEMM: h = x @ W (fp32, 64x64 tile, 4x4 per thread) ----------------
__global__ __launch_bounds__(256) void gemm_h(const float* __restrict__ x,
                                              const float* __restrict__ W,
                                              float* __restrict__ h) {
    __shared__ float As[16][64];
    __shared__ float Bs[16][64];
    const int tid = threadIdx.x;
    const int tx = tid & 15, ty = tid >> 4;
    const int m0 = blockIdx.y * 64;
    const int n0 = blockIdx.x * 64;
    const int lm = tid >> 2;          // 0..63 row within x tile
    const int lk = (tid & 3) * 4;     // k offset within 16
    const int wk = tid >> 4;          // 0..15 k row for W tile
    const int wn = (tid & 15) * 4;    // col offset within 64
    float acc[4][4] = {};
    for (int k0 = 0; k0 < FIN; k0 += 16) {
        float4 xa = *(const float4*)&x[(size_t)(m0 + lm) * FIN + k0 + lk];
        float4 wb = *(const float4*)&W[(size_t)(k0 + wk) * FOUT + n0 + wn];
        __syncthreads();
        As[lk + 0][lm] = xa.x;
        As[lk + 1][lm] = xa.y;
        As[lk + 2][lm] = xa.z;
        As[lk + 3][lm] = xa.w;
        *(float4*)&Bs[wk][wn] = wb;
        __syncthreads();
#pragma unroll
        for (int kk = 0; kk < 16; ++kk) {
            float av[4], bv[4];
            *(float4*)av = *(const float4*)&As[kk][ty * 4];
            *(float4*)bv = *(const float4*)&Bs[kk][tx * 4];
#pragma unroll
            for (int i = 0; i < 4; ++i)
#pragma unroll
                for (int j = 0; j < 4; ++j)
                    acc[i][j] = fmaf(av[i], bv[j], acc[i][j]);
        }
    }
#pragma unroll
    for (int i = 0; i < 4; ++i) {
        float4 v = make_float4(acc[i][0], acc[i][1], acc[i][2], acc[i][3]);
        *(float4*)&h[(size_t)(m0 + ty * 4 + i) * FOUT + n0 + tx * 4] = v;
    }
}

// ---------------- f = h@a1, g = h@a2 (block per row) ----------------
__global__ __launch_bounds__(256) void fg_kernel(const float* __restrict__ h,
                                                 const float* __restrict__ a,
                                                 float* __restrict__ f,
                                                 float* __restrict__ g) {
    const int i = blockIdx.x;
    const int c = threadIdx.x;
    float v = h[(size_t)i * FOUT + c];
    float p = v * a[c];
    float q = v * a[FOUT + c];
#pragma unroll
    for (int off = 32; off >= 1; off >>= 1) {
        p += __shfl_down(p, off, 64);
        q += __shfl_down(q, off, 64);
    }
    __shared__ float sp[4], sq[4];
    const int lane = c & 63, wid = c >> 6;
    if (lane == 0) { sp[wid] = p; sq[wid] = q; }
    __syncthreads();
    if (c == 0) {
        f[i] = sp[0] + sp[1] + sp[2] + sp[3];
        g[i] = sq[0] + sq[1] + sq[2] + sq[3];
    }
}

// ---------------- rank + scatter: replaces single-block bitonic sort ----------------
// rank_j = #{i : g_i < g_j  ||  (g_i == g_j && i < j)}  -- exact bijection 0..N-1
// 256 blocks x 256 threads; block handles 32 rows, 8 segments of 1024 elems each.
__global__ __launch_bounds__(256) void rank_scatter(const float* __restrict__ g,
                                                    float* __restrict__ gs,
                                                    int* __restrict__ perm) {
    const int t = threadIdx.x;
    const int jl = t & 31;        // row within block
    const int seg = t >> 5;       // 0..7
    const int j = blockIdx.x * 32 + jl;
    const float gj = g[j];
    const int base = seg * (NROWS / 8);
    int cnt = 0;
    for (int r = 0; r < NROWS / 8; r += 4) {
        const float4 v = *(const float4*)&g[base + r];
        const int i0 = base + r;
        cnt += (v.x < gj) || (v.x == gj && (i0 + 0) < j);
        cnt += (v.y < gj) || (v.y == gj && (i0 + 1) < j);
        cnt += (v.z < gj) || (v.z == gj && (i0 + 2) < j);
        cnt += (v.w < gj) || (v.w == gj && (i0 + 3) < j);
    }
    __shared__ int part[8][32];
    part[seg][jl] = cnt;
    __syncthreads();
    if (seg == 0) {
        int rank = 0;
#pragma unroll
        for (int s = 0; s < 8; ++s) rank += part[s][jl];
        gs[rank] = gj;
        perm[rank] = j;
    }
}

// ---------------- permute h into sorted order; compute weights ----------------
__global__ __launch_bounds__(256) void permute_kernel(const float* __restrict__ h,
                                                      const int* __restrict__ perm,
                                                      const float* __restrict__ gs,
                                                      const float* __restrict__ gmax,
                                                      float* __restrict__ hs,
                                                      float* __restrict__ wv) {
    const int r = blockIdx.x, c = threadIdx.x;
    const int src = perm[r];
    hs[(size_t)r * FOUT + c] = h[(size_t)src * FOUT + c];
    if (c == 0) wv[r] = expf(gs[r] - *gmax);
}

// ---------------- scans (3 passes) ----------------
__global__ __launch_bounds__(256) void scan_pass1(const float* __restrict__ hs,
                                                  const float* __restrict__ wv,
                                                  float* __restrict__ c0,
                                                  float* __restrict__ c1,
                                                  float* __restrict__ c1s) {
    const int k = blockIdx.x, c = threadIdx.x;
    const int base = k * CHROWS;
    float s0 = 0.f, s1 = 0.f;
    for (int r = 0; r < CHROWS; ++r) {
        float v = hs[(size_t)(base + r) * FOUT + c];
        float w = wv[base + r];
        s0 += v;
        s1 += w * v;
    }
    c0[k * FOUT + c] = s0;
    c1[k * FOUT + c] = s1;
    if (c == 0) {
        float t = 0.f;
        for (int r = 0; r < CHROWS; ++r) t += wv[base + r];
        c1s[k] = t;
    }
}

__global__ __launch_bounds__(256) void scan_pass2(const float* __restrict__ c0,
                                                  const float* __restrict__ c1,
                                                  const float* __restrict__ c1s,
                                                  float* __restrict__ o0,
                                                  float* __restrict__ o1,
                                                  float* __restrict__ o1s) {
    const int c = threadIdx.x;
    float run = 0.f;
    for (int k = 0; k < NCHUNK; ++k) { o0[k * FOUT + c] = run; run += c0[k * FOUT + c]; }
    float run1 = 0.f;
    for (int k = NCHUNK - 1; k >= 0; --k) { o1[k * FOUT + c] = run1; run1 += c1[k * FOUT + c]; }
    if (c == 0) {
        float rs = 0.f;
        for (int k = NCHUNK - 1; k >= 0; --k) { o1s[k] = rs; rs += c1s[k]; }
    }
}

__global__ __launch_bounds__(256) void scan_pass3(const float* __restrict__ hs,
                                                  const float* __restrict__ wv,
                                                  const float* __restrict__ o0,
                                                  const float* __restrict__ o1,
                                                  const float* __restrict__ o1s,
                                                  float* __restrict__ P0,
                                                  float* __restrict__ S1,
                                                  float* __restrict__ S1s) {
    const int k = blockIdx.x, c = threadIdx.x;
    const int base = k * CHROWS;
    float run0 = o0[k * FOUT + c];
    for (int r = 0; r < CHROWS; ++r) {
        P0[(size_t)(base + r) * FOUT + c] = run0;
        run0 += hs[(size_t)(base + r) * FOUT + c];
    }
    float run1 = o1[k * FOUT + c];
    for (int r = CHROWS - 1; r >= 0; --r) {
        float w = wv[base + r];
        float v = hs[(size_t)(base + r) * FOUT + c];
        run1 += w * v;
        S1[(size_t)(base + r) * FOUT + c] = run1;
    }
    if (c == 0) {
        float rs = o1s[k];
        for (int r = CHROWS - 1; r >= 0; --r) { rs += wv[base + r]; S1s[base + r] = rs; }
    }
    if (k == NCHUNK - 1) {
        P0[(size_t)NROWS * FOUT + c] = run0;   // total sum
        S1[(size_t)NROWS * FOUT + c] = 0.f;
        if (c == 0) S1s[NROWS] = 0.f;
    }
}

// ---------------- final: per-row combine + ELU ----------------
__global__ __launch_bounds__(256) void final_kernel(const float* __restrict__ f,
                                                    const float* __restrict__ gs,
                                                    const float* __restrict__ gmaxp,
                                                    const float* __restrict__ P0,
                                                    const float* __restrict__ S1,
                                                    const float* __restrict__ S1s,
                                                    float* __restrict__ out) {
    const int i = blockIdx.x, c = threadIdx.x;
    const float fi = f[i];
    const float gm = *gmaxp;
    const float t = -fi;
    int lo = 0, hi = NROWS;
    while (lo < hi) {
        int mid = (lo + hi) >> 1;
        if (gs[mid] <= t) lo = mid + 1; else hi = mid;
    }
    const int n0 = lo;  // count of g_j <= -f_i
    const float m = fmaxf(0.f, fi + gm);
    const float A = expf(-m);            // weight of relu-clipped group
    const float B = expf(fi + gm - m);   // scale of exp group
    const float denom = A * (float)n0 + B * S1s[n0];
    const float numer = A * P0[(size_t)n0 * FOUT + c] + B * S1[(size_t)n0 * FOUT + c];
    const float v = numer / denom;
    out[(size_t)i * FOUT + c] = v > 0.f ? v : expm1f(v);
}

extern "C" void kernel_launch(void* const* d_in, const int* in_sizes, int n_in,
                              void* d_out, int out_size, void* d_ws, size_t ws_size,
                              hipStream_t stream) {
    (void)in_sizes; (void)n_in; (void)out_size; (void)ws_size;
    const float* x = (const float*)d_in[0];
    const float* W = (const float*)d_in[1];
    const float* a = (const float*)d_in[2];
    float* out = (float*)d_out;

    char* ws = (char*)d_ws;
    size_t off = 0;
    auto alloc = [&](size_t bytes) -> void* {
        void* p = ws + off;
        off += (bytes + 255) & ~(size_t)255;
        return p;
    };
    float* h    = (float*)alloc((size_t)NROWS * FOUT * 4);
    float* hs   = (float*)alloc((size_t)NROWS * FOUT * 4);
    float* P0   = (float*)alloc((size_t)(NROWS + 1) * FOUT * 4);
    float* S1   = (float*)alloc((size_t)(NROWS + 1) * FOUT * 4);
    float* f    = (float*)alloc(NROWS * 4);
    float* g    = (float*)alloc(NROWS * 4);
    float* gs   = (float*)alloc(NROWS * 4);
    int*   perm = (int*)alloc(NROWS * 4);
    float* wv   = (float*)alloc(NROWS * 4);
    float* c0   = (float*)alloc(NCHUNK * FOUT * 4);
    float* c1   = (float*)alloc(NCHUNK * FOUT * 4);
    float* o0   = (float*)alloc(NCHUNK * FOUT * 4);
    float* o1   = (float*)alloc(NCHUNK * FOUT * 4);
    float* c1s  = (float*)alloc(NCHUNK * 4);
    float* o1s  = (float*)alloc(NCHUNK * 4);
    float* S1s  = (float*)alloc((NROWS + 1) * 4);

    gemm_h<<<dim3(FOUT / 64, NROWS / 64), 256, 0, stream>>>(x, W, h);
    fg_kernel<<<NROWS, 256, 0, stream>>>(h, a, f, g);
    rank_scatter<<<NROWS / 32, 256, 0, stream>>>(g, gs, perm);
    const float* gmaxp = gs + (NROWS - 1);   // sorted ascending: last element is max
    permute_kernel<<<NROWS, 256, 0, stream>>>(h, perm, gs, gmaxp, hs, wv);
    scan_pass1<<<NCHUNK, 256, 0, stream>>>(hs, wv, c0, c1, c1s);
    scan_pass2<<<1, 256, 0, stream>>>(c0, c1, c1s, o0, o1, o1s);
    scan_pass3<<<NCHUNK, 256, 0, stream>>>(hs, wv, o0, o1, o1s, P0, S1, S1s);
    final_kernel<<<NROWS, 256, 0, stream>>>(f, gs, gmaxp, P0, S1, S1s, out);
}

// Round 3
// 173.895 us; speedup vs baseline: 1.8920x; 1.0957x over previous
//
#include <hip/hip_runtime.h>
#include <math.h>

#define NROWS 8192
#define FIN   512
#define FOUT  256
#define NCHUNK 256
#define CHROWS 32   // NROWS / NCHUNK

// ---- GEMM h = x@W (fp32, 64x64 tile, BK=32, padded LDS, reg prefetch) ----
// Fused epilogue: f = h@a1, g = h@a2 via 16-lane shuffle reduce + atomicAdd.
__global__ __launch_bounds__(256) void gemm_fg(const float* __restrict__ x,
                                               const float* __restrict__ W,
                                               const float* __restrict__ a,
                                               float* __restrict__ h,
                                               float* __restrict__ f,
                                               float* __restrict__ g) {
    __shared__ float As[32][68];   // stride 68: As-write conflicts drop to 2-way (free)
    __shared__ float Bs[32][64];
    const int tid = threadIdx.x;
    const int tx = tid & 15, ty = tid >> 4;
    const int m0 = blockIdx.y * 64;
    const int n0 = blockIdx.x * 64;
    const int ar = tid >> 2;           // 0..63
    const int ak = (tid & 3) * 4;      // 0,4,8,12
    const int bk = tid >> 3;           // 0..31
    const int bn = (tid & 7) * 8;      // 0,8,...,56

    float4 a0 = *(const float4*)&x[(size_t)(m0 + ar) * FIN + ak];
    float4 a1 = *(const float4*)&x[(size_t)(m0 + ar) * FIN + ak + 16];
    float4 b0 = *(const float4*)&W[(size_t)bk * FOUT + n0 + bn];
    float4 b1 = *(const float4*)&W[(size_t)bk * FOUT + n0 + bn + 4];

    float acc[4][4] = {};
    for (int k0 = 0; k0 < FIN; k0 += 32) {
        __syncthreads();
        As[ak + 0][ar] = a0.x; As[ak + 1][ar] = a0.y;
        As[ak + 2][ar] = a0.z; As[ak + 3][ar] = a0.w;
        As[ak + 16][ar] = a1.x; As[ak + 17][ar] = a1.y;
        As[ak + 18][ar] = a1.z; As[ak + 19][ar] = a1.w;
        *(float4*)&Bs[bk][bn] = b0;
        *(float4*)&Bs[bk][bn + 4] = b1;
        __syncthreads();
        if (k0 + 32 < FIN) {   // prefetch next tile into regs, overlaps compute
            a0 = *(const float4*)&x[(size_t)(m0 + ar) * FIN + k0 + 32 + ak];
            a1 = *(const float4*)&x[(size_t)(m0 + ar) * FIN + k0 + 32 + ak + 16];
            b0 = *(const float4*)&W[(size_t)(k0 + 32 + bk) * FOUT + n0 + bn];
            b1 = *(const float4*)&W[(size_t)(k0 + 32 + bk) * FOUT + n0 + bn + 4];
        }
#pragma unroll
        for (int kk = 0; kk < 32; ++kk) {
            float av[4], bv[4];
            *(float4*)av = *(const float4*)&As[kk][ty * 4];
            *(float4*)bv = *(const float4*)&Bs[kk][tx * 4];
#pragma unroll
            for (int i = 0; i < 4; ++i)
#pragma unroll
                for (int j = 0; j < 4; ++j)
                    acc[i][j] = fmaf(av[i], bv[j], acc[i][j]);
        }
    }
    // write h
#pragma unroll
    for (int i = 0; i < 4; ++i) {
        float4 v = make_float4(acc[i][0], acc[i][1], acc[i][2], acc[i][3]);
        *(float4*)&h[(size_t)(m0 + ty * 4 + i) * FOUT + n0 + tx * 4] = v;
    }
    // fused f/g partials: reduce this block's 64-col strip, atomicAdd per row
    const float4 a1v = *(const float4*)&a[n0 + tx * 4];
    const float4 a2v = *(const float4*)&a[FOUT + n0 + tx * 4];
#pragma unroll
    for (int i = 0; i < 4; ++i) {
        float p = acc[i][0] * a1v.x + acc[i][1] * a1v.y + acc[i][2] * a1v.z + acc[i][3] * a1v.w;
        float q = acc[i][0] * a2v.x + acc[i][1] * a2v.y + acc[i][2] * a2v.z + acc[i][3] * a2v.w;
#pragma unroll
        for (int off = 8; off >= 1; off >>= 1) {
            p += __shfl_down(p, off, 16);
            q += __shfl_down(q, off, 16);
        }
        if (tx == 0) {
            atomicAdd(&f[m0 + ty * 4 + i], p);
            atomicAdd(&g[m0 + ty * 4 + i], q);
        }
    }
}

// ---- rank + scatter (replaces sort): rank_j = #{i: g_i<g_j || (==, i<j)} ----
__global__ __launch_bounds__(256) void rank_scatter(const float* __restrict__ g,
                                                    float* __restrict__ gs,
                                                    int* __restrict__ perm) {
    const int t = threadIdx.x;
    const int jl = t & 31;
    const int seg = t >> 5;
    const int j = blockIdx.x * 32 + jl;
    const float gj = g[j];
    const int base = seg * (NROWS / 8);
    int cnt = 0;
    for (int r = 0; r < NROWS / 8; r += 4) {
        const float4 v = *(const float4*)&g[base + r];
        const int i0 = base + r;
        cnt += (v.x < gj) || (v.x == gj && (i0 + 0) < j);
        cnt += (v.y < gj) || (v.y == gj && (i0 + 1) < j);
        cnt += (v.z < gj) || (v.z == gj && (i0 + 2) < j);
        cnt += (v.w < gj) || (v.w == gj && (i0 + 3) < j);
    }
    __shared__ int part[8][32];
    part[seg][jl] = cnt;
    __syncthreads();
    if (seg == 0) {
        int rank = 0;
#pragma unroll
        for (int s = 0; s < 8; ++s) rank += part[s][jl];
        gs[rank] = gj;
        perm[rank] = j;
    }
}

// ---- scan pass 1: per-chunk sums, gathering h rows via perm ----
__global__ __launch_bounds__(256) void scan_pass1(const float* __restrict__ h,
                                                  const int* __restrict__ perm,
                                                  const float* __restrict__ gs,
                                                  const float* __restrict__ gmaxp,
                                                  float* __restrict__ c0,
                                                  float* __restrict__ c1,
                                                  float* __restrict__ c1s) {
    const int k = blockIdx.x, c = threadIdx.x;
    const int base = k * CHROWS;
    __shared__ int p[CHROWS];
    __shared__ float wl[CHROWS];
    if (c < CHROWS) {
        p[c] = perm[base + c];
        wl[c] = expf(gs[base + c] - *gmaxp);
    }
    __syncthreads();
    float s0 = 0.f, s1 = 0.f;
    for (int r = 0; r < CHROWS; ++r) {
        float v = h[(size_t)p[r] * FOUT + c];
        s0 += v;
        s1 += wl[r] * v;
    }
    c0[k * FOUT + c] = s0;
    c1[k * FOUT + c] = s1;
    if (c == 0) {
        float t = 0.f;
        for (int r = 0; r < CHROWS; ++r) t += wl[r];
        c1s[k] = t;
    }
}

// ---- scan pass 2: chunk offsets. Parallel LDS suffix-scan for o1s; batched column scans ----
__global__ __launch_bounds__(256) void scan_pass2(const float* __restrict__ c0,
                                                  const float* __restrict__ c1,
                                                  const float* __restrict__ c1s,
                                                  float* __restrict__ o0,
                                                  float* __restrict__ o1,
                                                  float* __restrict__ o1s) {
    const int t = threadIdx.x;
    __shared__ float sb[NCHUNK];
    const float cv = c1s[t];
    sb[t] = cv;
    __syncthreads();
    for (int off = 1; off < NCHUNK; off <<= 1) {
        float v = sb[t] + ((t + off < NCHUNK) ? sb[t + off] : 0.f);
        __syncthreads();
        sb[t] = v;
        __syncthreads();
    }
    o1s[t] = sb[t] - cv;   // exclusive suffix sum

    float run = 0.f;
    for (int k = 0; k < NCHUNK; k += 8) {
        float v[8];
#pragma unroll
        for (int j = 0; j < 8; ++j) v[j] = c0[(k + j) * FOUT + t];
#pragma unroll
        for (int j = 0; j < 8; ++j) { o0[(k + j) * FOUT + t] = run; run += v[j]; }
    }
    float run1 = 0.f;
    for (int k = NCHUNK - 8; k >= 0; k -= 8) {
        float v[8];
#pragma unroll
        for (int j = 0; j < 8; ++j) v[j] = c1[(k + 7 - j) * FOUT + t];
#pragma unroll
        for (int j = 0; j < 8; ++j) { o1[(k + 7 - j) * FOUT + t] = run1; run1 += v[j]; }
    }
}

// ---- scan pass 3: final prefix/suffix arrays, gathering h via perm ----
__global__ __launch_bounds__(256) void scan_pass3(const float* __restrict__ h,
                                                  const int* __restrict__ perm,
                                                  const float* __restrict__ gs,
                                                  const float* __restrict__ gmaxp,
                                                  const float* __restrict__ o0,
                                                  const float* __restrict__ o1,
                                                  const float* __restrict__ o1s,
                                                  float* __restrict__ P0,
                                                  float* __restrict__ S1,
                                                  float* __restrict__ S1s) {
    const int k = blockIdx.x, c = threadIdx.x;
    const int base = k * CHROWS;
    __shared__ int p[CHROWS];
    __shared__ float wl[CHROWS];
    if (c < CHROWS) {
        p[c] = perm[base + c];
        wl[c] = expf(gs[base + c] - *gmaxp);
    }
    __syncthreads();
    float run0 = o0[k * FOUT + c];
    for (int r = 0; r < CHROWS; ++r) {
        P0[(size_t)(base + r) * FOUT + c] = run0;
        run0 += h[(size_t)p[r] * FOUT + c];
    }
    float run1 = o1[k * FOUT + c];
    for (int r = CHROWS - 1; r >= 0; --r) {
        run1 += wl[r] * h[(size_t)p[r] * FOUT + c];
        S1[(size_t)(base + r) * FOUT + c] = run1;
    }
    if (c == 0) {
        float rs = o1s[k];
        for (int r = CHROWS - 1; r >= 0; --r) { rs += wl[r]; S1s[base + r] = rs; }
    }
    if (k == NCHUNK - 1) {
        P0[(size_t)NROWS * FOUT + c] = run0;   // total column sum
        S1[(size_t)NROWS * FOUT + c] = 0.f;
        if (c == 0) S1s[NROWS] = 0.f;
    }
}

// ---- final: per-row binary search + combine + ELU ----
__global__ __launch_bounds__(256) void final_kernel(const float* __restrict__ f,
                                                    const float* __restrict__ gs,
                                                    const float* __restrict__ gmaxp,
                                                    const float* __restrict__ P0,
                                                    const float* __restrict__ S1,
                                                    const float* __restrict__ S1s,
                                                    float* __restrict__ out) {
    const int i = blockIdx.x, c = threadIdx.x;
    const float fi = f[i];
    const float gm = *gmaxp;
    const float t = -fi;
    int lo = 0, hi = NROWS;
    while (lo < hi) {
        int mid = (lo + hi) >> 1;
        if (gs[mid] <= t) lo = mid + 1; else hi = mid;
    }
    const int n0 = lo;  // count of g_j <= -f_i
    const float m = fmaxf(0.f, fi + gm);
    const float A = expf(-m);
    const float B = expf(fi + gm - m);
    const float denom = A * (float)n0 + B * S1s[n0];
    const float numer = A * P0[(size_t)n0 * FOUT + c] + B * S1[(size_t)n0 * FOUT + c];
    const float v = numer / denom;
    out[(size_t)i * FOUT + c] = v > 0.f ? v : expm1f(v);
}

extern "C" void kernel_launch(void* const* d_in, const int* in_sizes, int n_in,
                              void* d_out, int out_size, void* d_ws, size_t ws_size,
                              hipStream_t stream) {
    (void)in_sizes; (void)n_in; (void)out_size; (void)ws_size;
    const float* x = (const float*)d_in[0];
    const float* W = (const float*)d_in[1];
    const float* a = (const float*)d_in[2];
    float* out = (float*)d_out;

    char* ws = (char*)d_ws;
    size_t off = 0;
    auto alloc = [&](size_t bytes) -> void* {
        void* p = ws + off;
        off += (bytes + 255) & ~(size_t)255;
        return p;
    };
    float* h    = (float*)alloc((size_t)NROWS * FOUT * 4);
    float* P0   = (float*)alloc((size_t)(NROWS + 1) * FOUT * 4);
    float* S1   = (float*)alloc((size_t)(NROWS + 1) * FOUT * 4);
    float* fg   = (float*)alloc(2 * NROWS * 4);   // f then g, contiguous for one memset
    float* f    = fg;
    float* g    = fg + NROWS;
    float* gs   = (float*)alloc(NROWS * 4);
    int*   perm = (int*)alloc(NROWS * 4);
    float* c0   = (float*)alloc(NCHUNK * FOUT * 4);
    float* c1   = (float*)alloc(NCHUNK * FOUT * 4);
    float* o0   = (float*)alloc(NCHUNK * FOUT * 4);
    float* o1   = (float*)alloc(NCHUNK * FOUT * 4);
    float* c1s  = (float*)alloc(NCHUNK * 4);
    float* o1s  = (float*)alloc(NCHUNK * 4);
    float* S1s  = (float*)alloc((NROWS + 1) * 4);

    hipMemsetAsync(fg, 0, 2 * NROWS * 4, stream);
    gemm_fg<<<dim3(FOUT / 64, NROWS / 64), 256, 0, stream>>>(x, W, a, h, f, g);
    rank_scatter<<<NROWS / 32, 256, 0, stream>>>(g, gs, perm);
    const float* gmaxp = gs + (NROWS - 1);   // sorted ascending: max is last
    scan_pass1<<<NCHUNK, 256, 0, stream>>>(h, perm, gs, gmaxp, c0, c1, c1s);
    scan_pass2<<<1, 256, 0, stream>>>(c0, c1, c1s, o0, o1, o1s);
    scan_pass3<<<NCHUNK, 256, 0, stream>>>(h, perm, gs, gmaxp, o0, o1, o1s, P0, S1, S1s);
    final_kernel<<<NROWS, 256, 0, stream>>>(f, gs, gmaxp, P0, S1, S1s, out);
}

// Round 5
// 155.862 us; speedup vs baseline: 2.1109x; 1.1157x over previous
//
#include <hip/hip_runtime.h>
#include <math.h>

#define NROWS 8192
#define FIN   512
#define FOUT  256
#define NCHUNK 256
#define CHROWS 32   // NROWS / NCHUNK

typedef _Float16 f16;
typedef _Float16 f16x8 __attribute__((ext_vector_type(8)));
typedef float    f32x4 __attribute__((ext_vector_type(4)));

// ---- prep: x -> f16 (row-major), W -> Wt f16 transposed [N][K] ----
__global__ __launch_bounds__(256) void prep(const float* __restrict__ x,
                                            const float* __restrict__ W,
                                            f16* __restrict__ xh,
                                            f16* __restrict__ Wt) {
    const int b = blockIdx.x, t = threadIdx.x;
    if (b < 256) {
        const size_t base = (size_t)b * 16384;
#pragma unroll 4
        for (int i = 0; i < 16; ++i) {
            const size_t idx = base + (size_t)i * 1024 + t * 4;
            float4 v = *(const float4*)&x[idx];
            union { f16 h[4]; ushort4 u; } cv;
            cv.h[0] = (f16)v.x; cv.h[1] = (f16)v.y;
            cv.h[2] = (f16)v.z; cv.h[3] = (f16)v.w;
            *(ushort4*)&xh[idx] = cv.u;
        }
    } else {
        const int n = b - 256;   // 0..255
        Wt[(size_t)n * FIN + t]       = (f16)W[(size_t)t * FOUT + n];
        Wt[(size_t)n * FIN + t + 256] = (f16)W[(size_t)(t + 256) * FOUT + n];
    }
}

// ---- GEMM h = x@W via f16 MFMA 16x16x32; fused f/g epilogue (atomicAdd) ----
__global__ __launch_bounds__(256) void gemm_fg(const f16* __restrict__ xh,
                                               const f16* __restrict__ Wt,
                                               const float* __restrict__ a,
                                               float* __restrict__ h,
                                               float* __restrict__ f,
                                               float* __restrict__ g) {
    __shared__ __align__(16) f16 As[64][72];   // 72-half stride keeps b128 rows 16B-aligned
    __shared__ __align__(16) f16 Bs[64][72];
    __shared__ float sf[2][64], sg[2][64];
    const int tid = threadIdx.x;
    const int n0 = blockIdx.x * 64;
    const int m0 = blockIdx.y * 64;
    const int srow = tid >> 2, sseg = (tid & 3) * 8;
    const int w = tid >> 6, lane = tid & 63;
    const int wm = (w & 1) * 32, wn = (w >> 1) * 32;
    const int l15 = lane & 15, quad = lane >> 4;

    f16x8 pa0 = *(const f16x8*)&xh[(size_t)(m0 + srow) * FIN + sseg];
    f16x8 pa1 = *(const f16x8*)&xh[(size_t)(m0 + srow) * FIN + 32 + sseg];
    f16x8 pb0 = *(const f16x8*)&Wt[(size_t)(n0 + srow) * FIN + sseg];
    f16x8 pb1 = *(const f16x8*)&Wt[(size_t)(n0 + srow) * FIN + 32 + sseg];

    f32x4 acc[2][2] = {};
    for (int k0 = 0; k0 < FIN; k0 += 64) {
        __syncthreads();
        *(f16x8*)&As[srow][sseg] = pa0;
        *(f16x8*)&As[srow][32 + sseg] = pa1;
        *(f16x8*)&Bs[srow][sseg] = pb0;
        *(f16x8*)&Bs[srow][32 + sseg] = pb1;
        __syncthreads();
        if (k0 + 64 < FIN) {
            pa0 = *(const f16x8*)&xh[(size_t)(m0 + srow) * FIN + k0 + 64 + sseg];
            pa1 = *(const f16x8*)&xh[(size_t)(m0 + srow) * FIN + k0 + 96 + sseg];
            pb0 = *(const f16x8*)&Wt[(size_t)(n0 + srow) * FIN + k0 + 64 + sseg];
            pb1 = *(const f16x8*)&Wt[(size_t)(n0 + srow) * FIN + k0 + 96 + sseg];
        }
#pragma unroll
        for (int kk = 0; kk < 2; ++kk) {
            f16x8 af[2], bf[2];
#pragma unroll
            for (int ti = 0; ti < 2; ++ti)
                af[ti] = *(const f16x8*)&As[wm + ti * 16 + l15][kk * 32 + quad * 8];
#pragma unroll
            for (int tj = 0; tj < 2; ++tj)
                bf[tj] = *(const f16x8*)&Bs[wn + tj * 16 + l15][kk * 32 + quad * 8];
#pragma unroll
            for (int ti = 0; ti < 2; ++ti)
#pragma unroll
                for (int tj = 0; tj < 2; ++tj)
                    acc[ti][tj] = __builtin_amdgcn_mfma_f32_16x16x32_f16(af[ti], bf[tj], acc[ti][tj], 0, 0, 0);
        }
    }
    // write h (fp32): D layout col=lane&15, row=quad*4+r
#pragma unroll
    for (int ti = 0; ti < 2; ++ti)
#pragma unroll
        for (int tj = 0; tj < 2; ++tj) {
            const int col = n0 + wn + tj * 16 + l15;
#pragma unroll
            for (int r = 0; r < 4; ++r) {
                const int row = m0 + wm + ti * 16 + quad * 4 + r;
                h[(size_t)row * FOUT + col] = acc[ti][tj][r];
            }
        }
    // fused f/g partials over this block's 64-col strip -> atomicAdd per row
    const float a1c0 = a[n0 + wn + l15];
    const float a1c1 = a[n0 + wn + 16 + l15];
    const float a2c0 = a[FOUT + n0 + wn + l15];
    const float a2c1 = a[FOUT + n0 + wn + 16 + l15];
    const int wnIdx = w >> 1;
#pragma unroll
    for (int ti = 0; ti < 2; ++ti) {
        float pf[4], pg[4];
#pragma unroll
        for (int r = 0; r < 4; ++r) {
            pf[r] = acc[ti][0][r] * a1c0 + acc[ti][1][r] * a1c1;
            pg[r] = acc[ti][0][r] * a2c0 + acc[ti][1][r] * a2c1;
        }
#pragma unroll
        for (int off = 8; off >= 1; off >>= 1)
#pragma unroll
            for (int r = 0; r < 4; ++r) {
                pf[r] += __shfl_xor(pf[r], off, 16);
                pg[r] += __shfl_xor(pg[r], off, 16);
            }
        if (l15 == 0)
#pragma unroll
            for (int r = 0; r < 4; ++r) {
                sf[wnIdx][wm + ti * 16 + quad * 4 + r] = pf[r];
                sg[wnIdx][wm + ti * 16 + quad * 4 + r] = pg[r];
            }
    }
    __syncthreads();
    if (tid < 64) {
        atomicAdd(&f[m0 + tid], sf[0][tid] + sf[1][tid]);
        atomicAdd(&g[m0 + tid], sg[0][tid] + sg[1][tid]);
    }
}

// ---- rank + scatter: rank_j = #{i: g_i<g_j || (==, i<j)} ----
__global__ __launch_bounds__(256) void rank_scatter(const float* __restrict__ g,
                                                    float* __restrict__ gs,
                                                    int* __restrict__ perm) {
    const int t = threadIdx.x;
    const int jl = t & 31;
    const int seg = t >> 5;
    const int j = blockIdx.x * 32 + jl;
    const float gj = g[j];
    const int base = seg * (NROWS / 8);
    int cnt = 0;
    for (int r = 0; r < NROWS / 8; r += 4) {
        const float4 v = *(const float4*)&g[base + r];
        const int i0 = base + r;
        cnt += (v.x < gj) || (v.x == gj && (i0 + 0) < j);
        cnt += (v.y < gj) || (v.y == gj && (i0 + 1) < j);
        cnt += (v.z < gj) || (v.z == gj && (i0 + 2) < j);
        cnt += (v.w < gj) || (v.w == gj && (i0 + 3) < j);
    }
    __shared__ int part[8][32];
    part[seg][jl] = cnt;
    __syncthreads();
    if (seg == 0) {
        int rank = 0;
#pragma unroll
        for (int s = 0; s < 8; ++s) rank += part[s][jl];
        gs[rank] = gj;
        perm[rank] = j;
    }
}

// ---- scan pass 1: per-chunk sums, gathering h rows via perm ----
__global__ __launch_bounds__(256) void scan_pass1(const float* __restrict__ h,
                                                  const int* __restrict__ perm,
                                                  const float* __restrict__ gs,
                                                  const float* __restrict__ gmaxp,
                                                  float* __restrict__ c0,
                                                  float* __restrict__ c1,
                                                  float* __restrict__ c1s) {
    const int k = blockIdx.x, c = threadIdx.x;
    const int base = k * CHROWS;
    __shared__ int p[CHROWS];
    __shared__ float wl[CHROWS];
    if (c < CHROWS) {
        p[c] = perm[base + c];
        wl[c] = expf(gs[base + c] - *gmaxp);
    }
    __syncthreads();
    float s0 = 0.f, s1 = 0.f;
    for (int r = 0; r < CHROWS; ++r) {
        float v = h[(size_t)p[r] * FOUT + c];
        s0 += v;
        s1 += wl[r] * v;
    }
    c0[k * FOUT + c] = s0;
    c1[k * FOUT + c] = s1;
    if (c == 0) {
        float t = 0.f;
        for (int r = 0; r < CHROWS; ++r) t += wl[r];
        c1s[k] = t;
    }
}

// ---- scan pass 2: chunk offsets; parallel LDS suffix-scan for o1s ----
__global__ __launch_bounds__(256) void scan_pass2(const float* __restrict__ c0,
                                                  const float* __restrict__ c1,
                                                  const float* __restrict__ c1s,
                                                  float* __restrict__ o0,
                                                  float* __restrict__ o1,
                                                  float* __restrict__ o1s) {
    const int t = threadIdx.x;
    __shared__ float sb[NCHUNK];
    const float cv = c1s[t];
    sb[t] = cv;
    __syncthreads();
    for (int off = 1; off < NCHUNK; off <<= 1) {
        float v = sb[t] + ((t + off < NCHUNK) ? sb[t + off] : 0.f);
        __syncthreads();
        sb[t] = v;
        __syncthreads();
    }
    o1s[t] = sb[t] - cv;   // exclusive suffix sum

    float run = 0.f;
    for (int k = 0; k < NCHUNK; k += 8) {
        float v[8];
#pragma unroll
        for (int j = 0; j < 8; ++j) v[j] = c0[(k + j) * FOUT + t];
#pragma unroll
        for (int j = 0; j < 8; ++j) { o0[(k + j) * FOUT + t] = run; run += v[j]; }
    }
    float run1 = 0.f;
    for (int k = NCHUNK - 8; k >= 0; k -= 8) {
        float v[8];
#pragma unroll
        for (int j = 0; j < 8; ++j) v[j] = c1[(k + 7 - j) * FOUT + t];
#pragma unroll
        for (int j = 0; j < 8; ++j) { o1[(k + 7 - j) * FOUT + t] = run1; run1 += v[j]; }
    }
}

// ---- scan pass 3: final prefix/suffix arrays ----
__global__ __launch_bounds__(256) void scan_pass3(const float* __restrict__ h,
                                                  const int* __restrict__ perm,
                                                  const float* __restrict__ gs,
                                                  const float* __restrict__ gmaxp,
                                                  const float* __restrict__ o0,
                                                  const float* __restrict__ o1,
                                                  const float* __restrict__ o1s,
                                                  float* __restrict__ P0,
                                                  float* __restrict__ S1,
                                                  float* __restrict__ S1s) {
    const int k = blockIdx.x, c = threadIdx.x;
    const int base = k * CHROWS;
    __shared__ int p[CHROWS];
    __shared__ float wl[CHROWS];
    if (c < CHROWS) {
        p[c] = perm[base + c];
        wl[c] = expf(gs[base + c] - *gmaxp);
    }
    __syncthreads();
    float run0 = o0[k * FOUT + c];
    for (int r = 0; r < CHROWS; ++r) {
        P0[(size_t)(base + r) * FOUT + c] = run0;
        run0 += h[(size_t)p[r] * FOUT + c];
    }
    float run1 = o1[k * FOUT + c];
    for (int r = CHROWS - 1; r >= 0; --r) {
        run1 += wl[r] * h[(size_t)p[r] * FOUT + c];
        S1[(size_t)(base + r) * FOUT + c] = run1;
    }
    if (c == 0) {
        float rs = o1s[k];
        for (int r = CHROWS - 1; r >= 0; --r) { rs += wl[r]; S1s[base + r] = rs; }
    }
    if (k == NCHUNK - 1) {
        P0[(size_t)NROWS * FOUT + c] = run0;   // total column sum
        S1[(size_t)NROWS * FOUT + c] = 0.f;
        if (c == 0) S1s[NROWS] = 0.f;
    }
}

// ---- final: per-row binary search + combine + ELU ----
__global__ __launch_bounds__(256) void final_kernel(const float* __restrict__ f,
                                                    const float* __restrict__ gs,
                                                    const float* __restrict__ gmaxp,
                                                    const float* __restrict__ P0,
                                                    const float* __restrict__ S1,
                                                    const float* __restrict__ S1s,
                                                    float* __restrict__ out) {
    const int i = blockIdx.x, c = threadIdx.x;
    const float fi = f[i];
    const float gm = *gmaxp;
    const float t = -fi;
    int lo = 0, hi = NROWS;
    while (lo < hi) {
        int mid = (lo + hi) >> 1;
        if (gs[mid] <= t) lo = mid + 1; else hi = mid;
    }
    const int n0 = lo;  // count of g_j <= -f_i
    const float m = fmaxf(0.f, fi + gm);
    const float A = expf(-m);
    const float B = expf(fi + gm - m);
    const float denom = A * (float)n0 + B * S1s[n0];
    const float numer = A * P0[(size_t)n0 * FOUT + c] + B * S1[(size_t)n0 * FOUT + c];
    const float v = numer / denom;
    out[(size_t)i * FOUT + c] = v > 0.f ? v : expm1f(v);
}

extern "C" void kernel_launch(void* const* d_in, const int* in_sizes, int n_in,
                              void* d_out, int out_size, void* d_ws, size_t ws_size,
                              hipStream_t stream) {
    (void)in_sizes; (void)n_in; (void)out_size; (void)ws_size;
    const float* x = (const float*)d_in[0];
    const float* W = (const float*)d_in[1];
    const float* a = (const float*)d_in[2];
    float* out = (float*)d_out;

    char* ws = (char*)d_ws;
    size_t off = 0;
    auto alloc = [&](size_t bytes) -> void* {
        void* p = ws + off;
        off += (bytes + 255) & ~(size_t)255;
        return p;
    };
    f16*   xh   = (f16*)alloc((size_t)NROWS * FIN * 2);
    f16*   Wt   = (f16*)alloc((size_t)FOUT * FIN * 2);
    float* h    = (float*)alloc((size_t)NROWS * FOUT * 4);
    float* P0   = (float*)alloc((size_t)(NROWS + 1) * FOUT * 4);
    float* S1   = (float*)alloc((size_t)(NROWS + 1) * FOUT * 4);
    float* fg   = (float*)alloc(2 * NROWS * 4);   // f then g, one memset
    float* f    = fg;
    float* g    = fg + NROWS;
    float* gs   = (float*)alloc(NROWS * 4);
    int*   perm = (int*)alloc(NROWS * 4);
    float* c0   = (float*)alloc(NCHUNK * FOUT * 4);
    float* c1   = (float*)alloc(NCHUNK * FOUT * 4);
    float* o0   = (float*)alloc(NCHUNK * FOUT * 4);
    float* o1   = (float*)alloc(NCHUNK * FOUT * 4);
    float* c1s  = (float*)alloc(NCHUNK * 4);
    float* o1s  = (float*)alloc(NCHUNK * 4);
    float* S1s  = (float*)alloc((NROWS + 1) * 4);

    hipMemsetAsync(fg, 0, 2 * NROWS * 4, stream);
    prep<<<512, 256, 0, stream>>>(x, W, xh, Wt);
    gemm_fg<<<dim3(FOUT / 64, NROWS / 64), 256, 0, stream>>>(xh, Wt, a, h, f, g);
    rank_scatter<<<NROWS / 32, 256, 0, stream>>>(g, gs, perm);
    const float* gmaxp = gs + (NROWS - 1);   // sorted ascending: max is last
    scan_pass1<<<NCHUNK, 256, 0, stream>>>(h, perm, gs, gmaxp, c0, c1, c1s);
    scan_pass2<<<1, 256, 0, stream>>>(c0, c1, c1s, o0, o1, o1s);
    scan_pass3<<<NCHUNK, 256, 0, stream>>>(h, perm, gs, gmaxp, o0, o1, o1s, P0, S1, S1s);
    final_kernel<<<NROWS, 256, 0, stream>>>(f, gs, gmaxp, P0, S1, S1s, out);
}

// Round 6
// 135.469 us; speedup vs baseline: 2.4286x; 1.1505x over previous
//
#include <hip/hip_runtime.h>
#include <math.h>

#define NROWS 8192
#define FIN   512
#define FOUT  256
#define NCHUNK 256
#define CHROWS 32   // NROWS / NCHUNK

typedef _Float16 f16;
typedef _Float16 f16x8 __attribute__((ext_vector_type(8)));
typedef float    f32x4 __attribute__((ext_vector_type(4)));

// ---- prep: x -> f16, W -> Wt f16 transposed [N][K]; blocks 256-319 zero fg ----
__global__ __launch_bounds__(256) void prep(const float* __restrict__ x,
                                            const float* __restrict__ W,
                                            f16* __restrict__ xh,
                                            f16* __restrict__ Wt,
                                            float* __restrict__ fg) {
    const int b = blockIdx.x, t = threadIdx.x;
    if (b < 256) {
        const size_t base = (size_t)b * 16384;
#pragma unroll 4
        for (int i = 0; i < 16; ++i) {
            const size_t idx = base + (size_t)i * 1024 + t * 4;
            float4 v = *(const float4*)&x[idx];
            union { f16 h[4]; ushort4 u; } cv;
            cv.h[0] = (f16)v.x; cv.h[1] = (f16)v.y;
            cv.h[2] = (f16)v.z; cv.h[3] = (f16)v.w;
            *(ushort4*)&xh[idx] = cv.u;
        }
    } else {
        const int n = b - 256;   // 0..255
        Wt[(size_t)n * FIN + t]       = (f16)W[(size_t)t * FOUT + n];
        Wt[(size_t)n * FIN + t + 256] = (f16)W[(size_t)(t + 256) * FOUT + n];
        if (n < 64) fg[n * 256 + t] = 0.f;   // zero f and g (2*NROWS floats)
    }
}

// ---- GEMM h = x@W via f16 MFMA 16x16x32, BK=128; fused f/g epilogue ----
__global__ __launch_bounds__(256) void gemm_fg(const f16* __restrict__ xh,
                                               const f16* __restrict__ Wt,
                                               const float* __restrict__ a,
                                               float* __restrict__ h,
                                               float* __restrict__ f,
                                               float* __restrict__ g) {
    __shared__ __align__(16) f16 As[64][136];   // 136-half stride: 16B-aligned rows
    __shared__ __align__(16) f16 Bs[64][136];
    __shared__ float sf[2][64], sg[2][64];
    const int tid = threadIdx.x;
    const int n0 = blockIdx.x * 64;
    const int m0 = blockIdx.y * 64;
    const int srow = tid >> 2, sseg = (tid & 3) * 8;
    const int w = tid >> 6, lane = tid & 63;
    const int wm = (w & 1) * 32, wn = (w >> 1) * 32;
    const int l15 = lane & 15, quad = lane >> 4;

    f16x8 pa[4], pb[4];
#pragma unroll
    for (int j = 0; j < 4; ++j) {
        pa[j] = *(const f16x8*)&xh[(size_t)(m0 + srow) * FIN + j * 32 + sseg];
        pb[j] = *(const f16x8*)&Wt[(size_t)(n0 + srow) * FIN + j * 32 + sseg];
    }

    f32x4 acc[2][2] = {};
    for (int k0 = 0; k0 < FIN; k0 += 128) {
        __syncthreads();
#pragma unroll
        for (int j = 0; j < 4; ++j) {
            *(f16x8*)&As[srow][j * 32 + sseg] = pa[j];
            *(f16x8*)&Bs[srow][j * 32 + sseg] = pb[j];
        }
        __syncthreads();
        if (k0 + 128 < FIN) {
#pragma unroll
            for (int j = 0; j < 4; ++j) {
                pa[j] = *(const f16x8*)&xh[(size_t)(m0 + srow) * FIN + k0 + 128 + j * 32 + sseg];
                pb[j] = *(const f16x8*)&Wt[(size_t)(n0 + srow) * FIN + k0 + 128 + j * 32 + sseg];
            }
        }
#pragma unroll
        for (int kk = 0; kk < 4; ++kk) {
            f16x8 af[2], bf[2];
#pragma unroll
            for (int ti = 0; ti < 2; ++ti)
                af[ti] = *(const f16x8*)&As[wm + ti * 16 + l15][kk * 32 + quad * 8];
#pragma unroll
            for (int tj = 0; tj < 2; ++tj)
                bf[tj] = *(const f16x8*)&Bs[wn + tj * 16 + l15][kk * 32 + quad * 8];
#pragma unroll
            for (int ti = 0; ti < 2; ++ti)
#pragma unroll
                for (int tj = 0; tj < 2; ++tj)
                    acc[ti][tj] = __builtin_amdgcn_mfma_f32_16x16x32_f16(af[ti], bf[tj], acc[ti][tj], 0, 0, 0);
        }
    }
    // write h (fp32): D layout col=lane&15, row=quad*4+r
#pragma unroll
    for (int ti = 0; ti < 2; ++ti)
#pragma unroll
        for (int tj = 0; tj < 2; ++tj) {
            const int col = n0 + wn + tj * 16 + l15;
#pragma unroll
            for (int r = 0; r < 4; ++r) {
                const int row = m0 + wm + ti * 16 + quad * 4 + r;
                h[(size_t)row * FOUT + col] = acc[ti][tj][r];
            }
        }
    // fused f/g partials -> atomicAdd per row
    const float a1c0 = a[n0 + wn + l15];
    const float a1c1 = a[n0 + wn + 16 + l15];
    const float a2c0 = a[FOUT + n0 + wn + l15];
    const float a2c1 = a[FOUT + n0 + wn + 16 + l15];
    const int wnIdx = w >> 1;
#pragma unroll
    for (int ti = 0; ti < 2; ++ti) {
        float pf[4], pg[4];
#pragma unroll
        for (int r = 0; r < 4; ++r) {
            pf[r] = acc[ti][0][r] * a1c0 + acc[ti][1][r] * a1c1;
            pg[r] = acc[ti][0][r] * a2c0 + acc[ti][1][r] * a2c1;
        }
#pragma unroll
        for (int off = 8; off >= 1; off >>= 1)
#pragma unroll
            for (int r = 0; r < 4; ++r) {
                pf[r] += __shfl_xor(pf[r], off, 16);
                pg[r] += __shfl_xor(pg[r], off, 16);
            }
        if (l15 == 0)
#pragma unroll
            for (int r = 0; r < 4; ++r) {
                sf[wnIdx][wm + ti * 16 + quad * 4 + r] = pf[r];
                sg[wnIdx][wm + ti * 16 + quad * 4 + r] = pg[r];
            }
    }
    __syncthreads();
    if (tid < 64) {
        atomicAdd(&f[m0 + tid], sf[0][tid] + sf[1][tid]);
        atomicAdd(&g[m0 + tid], sg[0][tid] + sg[1][tid]);
    }
}

// ---- rank + scatter: rank_j = #{i: g_i<g_j || (==, i<j)} ----
__global__ __launch_bounds__(256) void rank_scatter(const float* __restrict__ g,
                                                    float* __restrict__ gs,
                                                    int* __restrict__ perm) {
    const int t = threadIdx.x;
    const int jl = t & 31;
    const int seg = t >> 5;
    const int j = blockIdx.x * 32 + jl;
    const float gj = g[j];
    const int base = seg * (NROWS / 8);
    int cnt = 0;
    for (int r = 0; r < NROWS / 8; r += 4) {
        const float4 v = *(const float4*)&g[base + r];
        const int i0 = base + r;
        cnt += (v.x < gj) || (v.x == gj && (i0 + 0) < j);
        cnt += (v.y < gj) || (v.y == gj && (i0 + 1) < j);
        cnt += (v.z < gj) || (v.z == gj && (i0 + 2) < j);
        cnt += (v.w < gj) || (v.w == gj && (i0 + 3) < j);
    }
    __shared__ int part[8][32];
    part[seg][jl] = cnt;
    __syncthreads();
    if (seg == 0) {
        int rank = 0;
#pragma unroll
        for (int s = 0; s < 8; ++s) rank += part[s][jl];
        gs[rank] = gj;
        perm[rank] = j;
    }
}

// ---- scan pass 1 (blocks 0-255): per-chunk sums; blocks 256-287: n0 searches ----
__global__ __launch_bounds__(256) void scan_pass1(const float* __restrict__ h,
                                                  const int* __restrict__ perm,
                                                  const float* __restrict__ gs,
                                                  const float* __restrict__ f,
                                                  float* __restrict__ c0,
                                                  float* __restrict__ c1,
                                                  float* __restrict__ c1s,
                                                  int* __restrict__ n0arr) {
    const int b = blockIdx.x, c = threadIdx.x;
    if (b < 256) {
        const int base = b * CHROWS;
        __shared__ int p[CHROWS];
        __shared__ float wl[CHROWS];
        if (c < CHROWS) {
            p[c] = perm[base + c];
            wl[c] = expf(gs[base + c] - gs[NROWS - 1]);
        }
        __syncthreads();
        float s0 = 0.f, s1 = 0.f;
        for (int r = 0; r < CHROWS; ++r) {
            float v = h[(size_t)p[r] * FOUT + c];
            s0 += v;
            s1 += wl[r] * v;
        }
        c0[b * FOUT + c] = s0;
        c1[b * FOUT + c] = s1;
        if (c == 0) {
            float t = 0.f;
            for (int r = 0; r < CHROWS; ++r) t += wl[r];
            c1s[b] = t;
        }
    } else {
        const int i = (b - 256) * 256 + c;   // 0..8191
        const float tt = -f[i];
        int lo = 0, hi = NROWS;
        while (lo < hi) {
            int mid = (lo + hi) >> 1;
            if (gs[mid] <= tt) lo = mid + 1; else hi = mid;
        }
        n0arr[i] = lo;
    }
}

// ---- scan pass 2 (parallel): per-column chunk-offset scans ----
__global__ __launch_bounds__(256) void scan_pass2(const float* __restrict__ c0,
                                                  const float* __restrict__ c1,
                                                  const float* __restrict__ c1s,
                                                  float* __restrict__ o0,
                                                  float* __restrict__ o1,
                                                  float* __restrict__ o1s) {
    const int b = blockIdx.x, t = threadIdx.x;
    __shared__ float sb[NCHUNK];
    if (b < 256) {
        // exclusive prefix over chunks of column b of c0
        const float cv = c0[t * FOUT + b];
        sb[t] = cv;
        __syncthreads();
        for (int off = 1; off < NCHUNK; off <<= 1) {
            float add = (t >= off) ? sb[t - off] : 0.f;
            __syncthreads();
            sb[t] += add;
            __syncthreads();
        }
        o0[t * FOUT + b] = sb[t] - cv;
    } else if (b < 512) {
        const int c = b - 256;
        // exclusive suffix over chunks of column c of c1
        const float cv = c1[t * FOUT + c];
        sb[t] = cv;
        __syncthreads();
        for (int off = 1; off < NCHUNK; off <<= 1) {
            float add = (t + off < NCHUNK) ? sb[t + off] : 0.f;
            __syncthreads();
            sb[t] += add;
            __syncthreads();
        }
        o1[t * FOUT + c] = sb[t] - cv;
    } else {
        // exclusive suffix over c1s
        const float cv = c1s[t];
        sb[t] = cv;
        __syncthreads();
        for (int off = 1; off < NCHUNK; off <<= 1) {
            float add = (t + off < NCHUNK) ? sb[t + off] : 0.f;
            __syncthreads();
            sb[t] += add;
            __syncthreads();
        }
        o1s[t] = sb[t] - cv;
    }
}

// ---- scan pass 3: element-granular P0 / S1 / S1s ----
__global__ __launch_bounds__(256) void scan_pass3(const float* __restrict__ h,
                                                  const int* __restrict__ perm,
                                                  const float* __restrict__ gs,
                                                  const float* __restrict__ o0,
                                                  const float* __restrict__ o1,
                                                  const float* __restrict__ o1s,
                                                  float* __restrict__ P0,
                                                  float* __restrict__ S1,
                                                  float* __restrict__ S1s) {
    const int k = blockIdx.x, c = threadIdx.x;
    const int base = k * CHROWS;
    __shared__ int p[CHROWS];
    __shared__ float wl[CHROWS];
    if (c < CHROWS) {
        p[c] = perm[base + c];
        wl[c] = expf(gs[base + c] - gs[NROWS - 1]);
    }
    __syncthreads();
    float run0 = o0[k * FOUT + c];
    for (int r = 0; r < CHROWS; ++r) {
        P0[(size_t)(base + r) * FOUT + c] = run0;
        run0 += h[(size_t)p[r] * FOUT + c];
    }
    float run1 = o1[k * FOUT + c];
    for (int r = CHROWS - 1; r >= 0; --r) {
        run1 += wl[r] * h[(size_t)p[r] * FOUT + c];
        S1[(size_t)(base + r) * FOUT + c] = run1;
    }
    if (c == 0) {
        float rs = o1s[k];
        for (int r = CHROWS - 1; r >= 0; --r) { rs += wl[r]; S1s[base + r] = rs; }
    }
    if (k == NCHUNK - 1) {
        P0[(size_t)NROWS * FOUT + c] = run0;   // total column sum
        S1[(size_t)NROWS * FOUT + c] = 0.f;
        if (c == 0) S1s[NROWS] = 0.f;
    }
}

// ---- final: streaming combine + ELU (search precomputed), 4 rows/block ----
__global__ __launch_bounds__(256) void final_kernel(const float* __restrict__ f,
                                                    const float* __restrict__ gs,
                                                    const int* __restrict__ n0arr,
                                                    const float* __restrict__ P0,
                                                    const float* __restrict__ S1,
                                                    const float* __restrict__ S1s,
                                                    float* __restrict__ out) {
    const int b = blockIdx.x, c = threadIdx.x;
    const float gm = gs[NROWS - 1];
#pragma unroll
    for (int rr = 0; rr < 4; ++rr) {
        const int i = b * 4 + rr;
        const float fi = f[i];
        const int n0 = n0arr[i];
        const float m = fmaxf(0.f, fi + gm);
        const float A = expf(-m);
        const float B = expf(fi + gm - m);
        const float denom = A * (float)n0 + B * S1s[n0];
        const float numer = A * P0[(size_t)n0 * FOUT + c] + B * S1[(size_t)n0 * FOUT + c];
        const float v = numer / denom;
        out[(size_t)i * FOUT + c] = v > 0.f ? v : expm1f(v);
    }
}

extern "C" void kernel_launch(void* const* d_in, const int* in_sizes, int n_in,
                              void* d_out, int out_size, void* d_ws, size_t ws_size,
                              hipStream_t stream) {
    (void)in_sizes; (void)n_in; (void)out_size; (void)ws_size;
    const float* x = (const float*)d_in[0];
    const float* W = (const float*)d_in[1];
    const float* a = (const float*)d_in[2];
    float* out = (float*)d_out;

    char* ws = (char*)d_ws;
    size_t off = 0;
    auto alloc = [&](size_t bytes) -> void* {
        void* p = ws + off;
        off += (bytes + 255) & ~(size_t)255;
        return p;
    };
    f16*   xh   = (f16*)alloc((size_t)NROWS * FIN * 2);
    f16*   Wt   = (f16*)alloc((size_t)FOUT * FIN * 2);
    float* h    = (float*)alloc((size_t)NROWS * FOUT * 4);
    float* P0   = (float*)alloc((size_t)(NROWS + 1) * FOUT * 4);
    float* S1   = (float*)alloc((size_t)(NROWS + 1) * FOUT * 4);
    float* fg   = (float*)alloc(2 * NROWS * 4);
    float* f    = fg;
    float* g    = fg + NROWS;
    float* gs   = (float*)alloc(NROWS * 4);
    int*   perm = (int*)alloc(NROWS * 4);
    int*   n0arr= (int*)alloc(NROWS * 4);
    float* c0   = (float*)alloc(NCHUNK * FOUT * 4);
    float* c1   = (float*)alloc(NCHUNK * FOUT * 4);
    float* o0   = (float*)alloc(NCHUNK * FOUT * 4);
    float* o1   = (float*)alloc(NCHUNK * FOUT * 4);
    float* c1s  = (float*)alloc(NCHUNK * 4);
    float* o1s  = (float*)alloc(NCHUNK * 4);
    float* S1s  = (float*)alloc((NROWS + 1) * 4);

    prep<<<512, 256, 0, stream>>>(x, W, xh, Wt, fg);
    gemm_fg<<<dim3(FOUT / 64, NROWS / 64), 256, 0, stream>>>(xh, Wt, a, h, f, g);
    rank_scatter<<<NROWS / 32, 256, 0, stream>>>(g, gs, perm);
    scan_pass1<<<288, 256, 0, stream>>>(h, perm, gs, f, c0, c1, c1s, n0arr);
    scan_pass2<<<513, 256, 0, stream>>>(c0, c1, c1s, o0, o1, o1s);
    scan_pass3<<<NCHUNK, 256, 0, stream>>>(h, perm, gs, o0, o1, o1s, P0, S1, S1s);
    final_kernel<<<NROWS / 4, 256, 0, stream>>>(f, gs, n0arr, P0, S1, S1s, out);
}